// Round 1
// baseline (261.478 us; speedup 1.0000x reference)
//
#include <hip/hip_runtime.h>
#include <hip/hip_bf16.h>
#include <math.h>

typedef unsigned short u16;
using short8 = __attribute__((ext_vector_type(8))) short;
using f32x4  = __attribute__((ext_vector_type(4))) float;

#define BM 128
#define BN 128
#define BK 32

// ---------- helpers ----------

__device__ __forceinline__ u16 f2bf(float f) {
  union { float f; unsigned u; } v; v.f = f;
  unsigned r = v.u + 0x7FFFu + ((v.u >> 16) & 1u);   // RNE
  return (u16)(r >> 16);
}

__device__ __forceinline__ void gld16(const void* g, void* l) {
  __builtin_amdgcn_global_load_lds(
      (const __attribute__((address_space(1))) void*)g,
      (__attribute__((address_space(3))) void*)l,
      16, 0, 0);
}

// ---------- shared GEMM core (m97 pattern) ----------
// Computes 128x128 C tile of A[M,K] @ Bt[N,K]^T. Both operands row-major with
// K contiguous (bf16 as u16). 256 threads = 4 waves in 2x2 (64x64 per wave,
// 4x4 MFMA 16x16x32 tiles). K % 32 == 0.

__device__ __forceinline__ void gemm_core(const u16* __restrict__ Ag,
                                          const u16* __restrict__ Bg,
                                          int K, u16* As, u16* Bs,
                                          f32x4 acc[4][4]) {
  const int tid = threadIdx.x;
  const int w = tid >> 6, l = tid & 63;
  const int wm = (w & 1) << 6, wn = (w >> 1) << 6;
  const int ln = l & 15, lq = l >> 4;
  // staging: wave w + chunk c cover 16 rows each; lane layout is exactly
  // base + lane*16B so global_load_lds's uniform-base+lane*size matches.
  const int sr0 = w * 16 + (l >> 2);
  const int sr1 = 64 + sr0;
  const int sk = (l & 3) * 8;

#pragma unroll
  for (int mt = 0; mt < 4; mt++)
#pragma unroll
    for (int nt = 0; nt < 4; nt++) acc[mt][nt] = (f32x4)0.0f;

  for (int k0 = 0; k0 < K; k0 += BK) {
    __syncthreads();
    gld16(Ag + (size_t)sr0 * K + k0 + sk, As + sr0 * BK + sk);
    gld16(Ag + (size_t)sr1 * K + k0 + sk, As + sr1 * BK + sk);
    gld16(Bg + (size_t)sr0 * K + k0 + sk, Bs + sr0 * BK + sk);
    gld16(Bg + (size_t)sr1 * K + k0 + sk, Bs + sr1 * BK + sk);
    __syncthreads();
    short8 af[4], bf[4];
#pragma unroll
    for (int mt = 0; mt < 4; mt++)
      af[mt] = *(const short8*)(As + (wm + mt * 16 + ln) * BK + lq * 8);
#pragma unroll
    for (int nt = 0; nt < 4; nt++)
      bf[nt] = *(const short8*)(Bs + (wn + nt * 16 + ln) * BK + lq * 8);
#pragma unroll
    for (int mt = 0; mt < 4; mt++)
#pragma unroll
      for (int nt = 0; nt < 4; nt++)
        acc[mt][nt] = __builtin_amdgcn_mfma_f32_16x16x32_bf16(
            af[mt], bf[nt], acc[mt][nt], 0, 0, 0);
  }
}

// ---------- conversion kernels ----------

__global__ __launch_bounds__(256) void k_convx(const float* __restrict__ x,
                                               u16* __restrict__ xb, int n4) {
  int i = blockIdx.x * 256 + threadIdx.x;
  if (i < n4) {
    float4 v = ((const float4*)x)[i];
    ushort4 o;
    o.x = f2bf(v.x); o.y = f2bf(v.y); o.z = f2bf(v.z); o.w = f2bf(v.w);
    ((ushort4*)xb)[i] = o;
  }
}

// Wt[1536][256] = concat(Wq,Wk,Wv)^T in bf16; bcat[1536] = concat biases.
__global__ __launch_bounds__(256) void k_convw(
    const float* __restrict__ Wq, const float* __restrict__ Wk,
    const float* __restrict__ Wv, const float* __restrict__ bq,
    const float* __restrict__ bk, const float* __restrict__ bv,
    u16* __restrict__ Wt, float* __restrict__ bcat) {
  int i = blockIdx.x * 256 + threadIdx.x;   // 1536*256 threads
  if (i < 1536 * 256) {
    int nn = i >> 8, e = i & 255;
    int sel = nn >> 9, c = nn & 511;
    const float* W = (sel == 0) ? Wq : (sel == 1) ? Wk : Wv;
    Wt[i] = f2bf(W[e * 512 + c]);           // W is [256][512] row-major
    if (e == 0) {
      const float* bb = (sel == 0) ? bq : (sel == 1) ? bk : bv;
      bcat[nn] = bb[c];
    }
  }
}

// ---------- projection GEMM: [16384,256] @ Wt^T -> q(sigmoid),k,v bf16 ----------

__global__ __launch_bounds__(256) void k_proj(
    const u16* __restrict__ xb, const u16* __restrict__ Wt,
    const float* __restrict__ bcat, u16* __restrict__ qb,
    u16* __restrict__ kb, u16* __restrict__ vb) {
  __shared__ __align__(16) u16 As[BM * BK];
  __shared__ __align__(16) u16 Bs[BN * BK];
  const int bm = blockIdx.y * BM, bn = blockIdx.x * BN;
  f32x4 acc[4][4];
  gemm_core(xb + (size_t)bm * 256, Wt + (size_t)bn * 256, 256, As, Bs, acc);

  const int tid = threadIdx.x, w = tid >> 6, l = tid & 63;
  const int wm = (w & 1) << 6, wn = (w >> 1) << 6;
  const int ln = l & 15, lq = l >> 4;
#pragma unroll
  for (int mt = 0; mt < 4; mt++)
#pragma unroll
    for (int r = 0; r < 4; r++) {
      int row = bm + wm + mt * 16 + lq * 4 + r;
#pragma unroll
      for (int nt = 0; nt < 4; nt++) {
        int col = bn + wn + nt * 16 + ln;
        float v = acc[mt][nt][r] + bcat[col];
        int sel = col >> 9, c2 = col & 511;
        float ov = (sel == 0) ? (1.0f / (1.0f + expf(-v))) : v;
        u16* dst = (sel == 0) ? qb : (sel == 1) ? kb : vb;
        dst[(size_t)row * 512 + c2] = f2bf(ov);
      }
    }
}

// ---------- V transpose: vb[b][t][v] -> vtb[b][v][t] ----------

__global__ __launch_bounds__(256) void k_transv(const u16* __restrict__ vb,
                                                u16* __restrict__ vtb) {
  const int b = blockIdx.z;
  const int t0 = blockIdx.y * 64, v0 = blockIdx.x * 64;
  __shared__ u16 tl[64][65];
  const u16* src = vb + (size_t)b * 2048 * 512;
  u16* dst = vtb + (size_t)b * 512 * 2048;
  for (int i = threadIdx.x; i < 4096; i += 256) {
    int r = i >> 6, c = i & 63;
    tl[r][c] = src[(size_t)(t0 + r) * 512 + v0 + c];
  }
  __syncthreads();
  for (int i = threadIdx.x; i < 4096; i += 256) {
    int r = i >> 6, c = i & 63;
    dst[(size_t)(v0 + r) * 2048 + t0 + c] = tl[c][r];
  }
}

// ---------- QK^T + elu + exp -> P (bf16), row sums via atomics ----------

__global__ __launch_bounds__(256) void k_qk(const u16* __restrict__ qb,
                                            const u16* __restrict__ kb,
                                            u16* __restrict__ P,
                                            float* __restrict__ lsum) {
  __shared__ __align__(16) u16 As[BM * BK];
  __shared__ __align__(16) u16 Bs[BN * BK];
  const int b = blockIdx.z;
  const int bm = blockIdx.y * BM, bn = blockIdx.x * BN;
  const size_t ob = (size_t)b * 2048 * 512;
  f32x4 acc[4][4];
  gemm_core(qb + ob + (size_t)bm * 512, kb + ob + (size_t)bn * 512, 512, As, Bs, acc);

  const int tid = threadIdx.x, w = tid >> 6, l = tid & 63;
  const int wm = (w & 1) << 6, wn = (w >> 1) << 6;
  const int ln = l & 15, lq = l >> 4;
  const float scale = 0.0625f;  // 1/sqrt(256)
#pragma unroll
  for (int mt = 0; mt < 4; mt++)
#pragma unroll
    for (int r = 0; r < 4; r++) {
      int row = bm + wm + mt * 16 + lq * 4 + r;
      float s = 0.0f;
#pragma unroll
      for (int nt = 0; nt < 4; nt++) {
        int col = bn + wn + nt * 16 + ln;
        float v = acc[mt][nt][r] * scale;
        float e = (v > 0.0f) ? v : expm1f(v);   // elu
        float p = expf(e);                       // unnormalized softmax (no max needed)
        P[((size_t)b * 2048 + row) * 2048 + col] = f2bf(p);
        s += p;
      }
      // reduce over the 16 lanes (ln) that share this row
#pragma unroll
      for (int o = 1; o < 16; o <<= 1) s += __shfl_xor(s, o);
      if (ln == 0) atomicAdd(&lsum[b * 2048 + row], s);
    }
}

// ---------- P @ V, divide by row sum, fp32 out ----------

__global__ __launch_bounds__(256) void k_pv(const u16* __restrict__ P,
                                            const u16* __restrict__ vtb,
                                            const float* __restrict__ lsum,
                                            float* __restrict__ out) {
  __shared__ __align__(16) u16 As[BM * BK];
  __shared__ __align__(16) u16 Bs[BN * BK];
  const int b = blockIdx.z;
  const int bm = blockIdx.y * BM, bn = blockIdx.x * BN;
  f32x4 acc[4][4];
  gemm_core(P + (size_t)b * 2048 * 2048 + (size_t)bm * 2048,
            vtb + (size_t)b * 512 * 2048 + (size_t)bn * 2048, 2048, As, Bs, acc);

  const int tid = threadIdx.x, w = tid >> 6, l = tid & 63;
  const int wm = (w & 1) << 6, wn = (w >> 1) << 6;
  const int ln = l & 15, lq = l >> 4;
#pragma unroll
  for (int mt = 0; mt < 4; mt++)
#pragma unroll
    for (int r = 0; r < 4; r++) {
      int row = bm + wm + mt * 16 + lq * 4 + r;
      float inv = 1.0f / lsum[b * 2048 + row];
#pragma unroll
      for (int nt = 0; nt < 4; nt++) {
        int col = bn + wn + nt * 16 + ln;
        out[((size_t)b * 2048 + row) * 512 + col] = acc[mt][nt][r] * inv;
      }
    }
}

// ---------- launch ----------

extern "C" void kernel_launch(void* const* d_in, const int* in_sizes, int n_in,
                              void* d_out, int out_size, void* d_ws, size_t ws_size,
                              hipStream_t stream) {
  const float* x  = (const float*)d_in[0];
  const float* Wq = (const float*)d_in[1];
  const float* bq = (const float*)d_in[2];
  const float* Wk = (const float*)d_in[3];
  const float* bk = (const float*)d_in[4];
  const float* Wv = (const float*)d_in[5];
  const float* bv = (const float*)d_in[6];
  float* out = (float*)d_out;
  char* ws = (char*)d_ws;

  // workspace layout (bytes). P aliases xb/Wt/bcat/vb which are dead before
  // k_qk writes P. Total required: ~117.5 MB.
  u16*  qb   = (u16*)(ws + 0);            // 16,777,216
  u16*  kb   = (u16*)(ws + 16777216);     // 16,777,216
  u16*  vtb  = (u16*)(ws + 33554432);     // 16,777,216
  float* lsum = (float*)(ws + 50331648);  //     65,536
  u16*  P    = (u16*)(ws + 50397184);     // 67,108,864 (ends 117,506,048)
  u16*  xb   = (u16*)(ws + 50397184);     //  8,388,608 (alias P)
  u16*  Wt   = (u16*)(ws + 58785792);     //    786,432 (alias P)
  float* bcat = (float*)(ws + 59572224);  //      6,144 (alias P)
  u16*  vb   = (u16*)(ws + 59578368);     // 16,777,216 (alias P)

  // 1. convert x -> bf16
  k_convx<<<4096, 256, 0, stream>>>(x, xb, 16384 * 256 / 4);
  // 2. build transposed bf16 weights + concat bias
  k_convw<<<1536, 256, 0, stream>>>(Wq, Wk, Wv, bq, bk, bv, Wt, bcat);
  // 3. fused QKV projection GEMM (N = 1536)
  k_proj<<<dim3(12, 128, 1), 256, 0, stream>>>(xb, Wt, bcat, qb, kb, vb);
  // 4. transpose V for the PV B-operand
  k_transv<<<dim3(8, 32, 8), 256, 0, stream>>>(vb, vtb);
  // 5. zero the row sums (ws is poisoned each call)
  hipMemsetAsync(lsum, 0, 16384 * sizeof(float), stream);
  // 6. QK^T -> P = exp(elu(qk/16)) bf16 + row sums
  k_qk<<<dim3(16, 16, 8), 256, 0, stream>>>(qb, kb, P, lsum);
  // 7. out = (P @ V) / lsum
  k_pv<<<dim3(4, 16, 8), 256, 0, stream>>>(P, vtb, lsum, out);
}

// Round 2
// 238.913 us; speedup vs baseline: 1.0945x; 1.0945x over previous
//
#include <hip/hip_runtime.h>
#include <hip/hip_bf16.h>
#include <math.h>

typedef unsigned short u16;
using short8 = __attribute__((ext_vector_type(8))) short;
using f32x4  = __attribute__((ext_vector_type(4))) float;

#define BM 128
#define BN 128
#define BK 32

// ---------- helpers ----------

__device__ __forceinline__ u16 f2bf(float f) {
  union { float f; unsigned u; } v; v.f = f;
  unsigned r = v.u + 0x7FFFu + ((v.u >> 16) & 1u);   // RNE
  return (u16)(r >> 16);
}

// hardware exp: v_mul + v_exp_f32 (vs ~20-35 inst libm expf). Inputs here are
// bounded (|logit| <~ 8, elu in (-1, 8]) so no range-reduction needed.
__device__ __forceinline__ float fexp(float x) { return __expf(x); }

__device__ __forceinline__ void gld16(const void* g, void* l) {
  __builtin_amdgcn_global_load_lds(
      (const __attribute__((address_space(1))) void*)g,
      (__attribute__((address_space(3))) void*)l,
      16, 0, 0);
}

// ---------- shared GEMM core (m97 pattern) ----------
// Computes 128x128 C tile of A[M,K] @ Bt[N,K]^T. Both operands row-major with
// K contiguous (bf16 as u16). 256 threads = 4 waves in 2x2 (64x64 per wave,
// 4x4 MFMA 16x16x32 tiles). K % 32 == 0.

__device__ __forceinline__ void gemm_core(const u16* __restrict__ Ag,
                                          const u16* __restrict__ Bg,
                                          int K, u16* As, u16* Bs,
                                          f32x4 acc[4][4]) {
  const int tid = threadIdx.x;
  const int w = tid >> 6, l = tid & 63;
  const int wm = (w & 1) << 6, wn = (w >> 1) << 6;
  const int ln = l & 15, lq = l >> 4;
  const int sr0 = w * 16 + (l >> 2);
  const int sr1 = 64 + sr0;
  const int sk = (l & 3) * 8;

#pragma unroll
  for (int mt = 0; mt < 4; mt++)
#pragma unroll
    for (int nt = 0; nt < 4; nt++) acc[mt][nt] = (f32x4)0.0f;

  for (int k0 = 0; k0 < K; k0 += BK) {
    __syncthreads();
    gld16(Ag + (size_t)sr0 * K + k0 + sk, As + sr0 * BK + sk);
    gld16(Ag + (size_t)sr1 * K + k0 + sk, As + sr1 * BK + sk);
    gld16(Bg + (size_t)sr0 * K + k0 + sk, Bs + sr0 * BK + sk);
    gld16(Bg + (size_t)sr1 * K + k0 + sk, Bs + sr1 * BK + sk);
    __syncthreads();
    short8 af[4], bf[4];
#pragma unroll
    for (int mt = 0; mt < 4; mt++)
      af[mt] = *(const short8*)(As + (wm + mt * 16 + ln) * BK + lq * 8);
#pragma unroll
    for (int nt = 0; nt < 4; nt++)
      bf[nt] = *(const short8*)(Bs + (wn + nt * 16 + ln) * BK + lq * 8);
#pragma unroll
    for (int mt = 0; mt < 4; mt++)
#pragma unroll
      for (int nt = 0; nt < 4; nt++)
        acc[mt][nt] = __builtin_amdgcn_mfma_f32_16x16x32_bf16(
            af[mt], bf[nt], acc[mt][nt], 0, 0, 0);
  }
}

// ---------- conversion kernels ----------

__global__ __launch_bounds__(256) void k_convx(const float* __restrict__ x,
                                               u16* __restrict__ xb, int n4) {
  int i = blockIdx.x * 256 + threadIdx.x;
  if (i < n4) {
    float4 v = ((const float4*)x)[i];
    ushort4 o;
    o.x = f2bf(v.x); o.y = f2bf(v.y); o.z = f2bf(v.z); o.w = f2bf(v.w);
    ((ushort4*)xb)[i] = o;
  }
}

// Wt[1536][256] = concat(Wq,Wk,Wv)^T in bf16; bcat[1536] = concat biases.
__global__ __launch_bounds__(256) void k_convw(
    const float* __restrict__ Wq, const float* __restrict__ Wk,
    const float* __restrict__ Wv, const float* __restrict__ bq,
    const float* __restrict__ bk, const float* __restrict__ bv,
    u16* __restrict__ Wt, float* __restrict__ bcat) {
  int i = blockIdx.x * 256 + threadIdx.x;   // 1536*256 threads
  if (i < 1536 * 256) {
    int nn = i >> 8, e = i & 255;
    int sel = nn >> 9, c = nn & 511;
    const float* W = (sel == 0) ? Wq : (sel == 1) ? Wk : Wv;
    Wt[i] = f2bf(W[e * 512 + c]);           // W is [256][512] row-major
    if (e == 0) {
      const float* bb = (sel == 0) ? bq : (sel == 1) ? bk : bv;
      bcat[nn] = bb[c];
    }
  }
}

// ---------- projection GEMM: [16384,256] @ Wt^T -> q(sigmoid),k,v bf16 ----------

__global__ __launch_bounds__(256) void k_proj(
    const u16* __restrict__ xb, const u16* __restrict__ Wt,
    const float* __restrict__ bcat, u16* __restrict__ qb,
    u16* __restrict__ kb, u16* __restrict__ vb) {
  __shared__ __align__(16) u16 As[BM * BK];
  __shared__ __align__(16) u16 Bs[BN * BK];
  const int bm = blockIdx.y * BM, bn = blockIdx.x * BN;
  f32x4 acc[4][4];
  gemm_core(xb + (size_t)bm * 256, Wt + (size_t)bn * 256, 256, As, Bs, acc);

  const int tid = threadIdx.x, w = tid >> 6, l = tid & 63;
  const int wm = (w & 1) << 6, wn = (w >> 1) << 6;
  const int ln = l & 15, lq = l >> 4;
#pragma unroll
  for (int mt = 0; mt < 4; mt++)
#pragma unroll
    for (int r = 0; r < 4; r++) {
      int row = bm + wm + mt * 16 + lq * 4 + r;
#pragma unroll
      for (int nt = 0; nt < 4; nt++) {
        int col = bn + wn + nt * 16 + ln;
        float v = acc[mt][nt][r] + bcat[col];
        int sel = col >> 9, c2 = col & 511;
        // fast sigmoid: hw exp + hw rcp (output is bf16 anyway)
        float sg = __builtin_amdgcn_rcpf(1.0f + fexp(-v));
        float ov = (sel == 0) ? sg : v;
        u16* dst = (sel == 0) ? qb : (sel == 1) ? kb : vb;
        dst[(size_t)row * 512 + c2] = f2bf(ov);
      }
    }
}

// ---------- V transpose: vb[b][t][v] -> vtb[b][v][t] ----------

__global__ __launch_bounds__(256) void k_transv(const u16* __restrict__ vb,
                                                u16* __restrict__ vtb) {
  const int b = blockIdx.z;
  const int t0 = blockIdx.y * 64, v0 = blockIdx.x * 64;
  __shared__ u16 tl[64][65];
  const u16* src = vb + (size_t)b * 2048 * 512;
  u16* dst = vtb + (size_t)b * 512 * 2048;
  for (int i = threadIdx.x; i < 4096; i += 256) {
    int r = i >> 6, c = i & 63;
    tl[r][c] = src[(size_t)(t0 + r) * 512 + v0 + c];
  }
  __syncthreads();
  for (int i = threadIdx.x; i < 4096; i += 256) {
    int r = i >> 6, c = i & 63;
    dst[(size_t)(v0 + r) * 2048 + t0 + c] = tl[c][r];
  }
}

// ---------- QK^T + elu + exp -> P (bf16), row sums via atomics ----------

__global__ __launch_bounds__(256) void k_qk(const u16* __restrict__ qb,
                                            const u16* __restrict__ kb,
                                            u16* __restrict__ P,
                                            float* __restrict__ lsum) {
  __shared__ __align__(16) u16 As[BM * BK];
  __shared__ __align__(16) u16 Bs[BN * BK];
  const int b = blockIdx.z;
  const int bm = blockIdx.y * BM, bn = blockIdx.x * BN;
  const size_t ob = (size_t)b * 2048 * 512;
  f32x4 acc[4][4];
  gemm_core(qb + ob + (size_t)bm * 512, kb + ob + (size_t)bn * 512, 512, As, Bs, acc);

  const int tid = threadIdx.x, w = tid >> 6, l = tid & 63;
  const int wm = (w & 1) << 6, wn = (w >> 1) << 6;
  const int ln = l & 15, lq = l >> 4;
  const float scale = 0.0625f;  // 1/sqrt(256)
#pragma unroll
  for (int mt = 0; mt < 4; mt++)
#pragma unroll
    for (int r = 0; r < 4; r++) {
      int row = bm + wm + mt * 16 + lq * 4 + r;
      float s = 0.0f;
#pragma unroll
      for (int nt = 0; nt < 4; nt++) {
        int col = bn + wn + nt * 16 + ln;
        float v = acc[mt][nt][r] * scale;
        // elu then exp, all in hw-exp. expm1 ~ exp-1: cancellation error
        // ~2^-24 absolute, invisible under bf16 storage of p.
        float e = (v > 0.0f) ? v : (fexp(v) - 1.0f);
        float p = fexp(e);      // unnormalized softmax (elu>=-1 so no max sub)
        P[((size_t)b * 2048 + row) * 2048 + col] = f2bf(p);
        s += p;
      }
      // reduce over the 16 lanes (ln) that share this row
#pragma unroll
      for (int o = 1; o < 16; o <<= 1) s += __shfl_xor(s, o);
      if (ln == 0) atomicAdd(&lsum[b * 2048 + row], s);
    }
}

// ---------- P @ V, divide by row sum, fp32 out ----------

__global__ __launch_bounds__(256) void k_pv(const u16* __restrict__ P,
                                            const u16* __restrict__ vtb,
                                            const float* __restrict__ lsum,
                                            float* __restrict__ out) {
  __shared__ __align__(16) u16 As[BM * BK];
  __shared__ __align__(16) u16 Bs[BN * BK];
  const int b = blockIdx.z;
  const int bm = blockIdx.y * BM, bn = blockIdx.x * BN;
  f32x4 acc[4][4];
  gemm_core(P + (size_t)b * 2048 * 2048 + (size_t)bm * 2048,
            vtb + (size_t)b * 512 * 2048 + (size_t)bn * 2048, 2048, As, Bs, acc);

  const int tid = threadIdx.x, w = tid >> 6, l = tid & 63;
  const int wm = (w & 1) << 6, wn = (w >> 1) << 6;
  const int ln = l & 15, lq = l >> 4;
#pragma unroll
  for (int mt = 0; mt < 4; mt++)
#pragma unroll
    for (int r = 0; r < 4; r++) {
      int row = bm + wm + mt * 16 + lq * 4 + r;
      float inv = 1.0f / lsum[b * 2048 + row];
#pragma unroll
      for (int nt = 0; nt < 4; nt++) {
        int col = bn + wn + nt * 16 + ln;
        out[((size_t)b * 2048 + row) * 512 + col] = acc[mt][nt][r] * inv;
      }
    }
}

// ---------- launch ----------

extern "C" void kernel_launch(void* const* d_in, const int* in_sizes, int n_in,
                              void* d_out, int out_size, void* d_ws, size_t ws_size,
                              hipStream_t stream) {
  const float* x  = (const float*)d_in[0];
  const float* Wq = (const float*)d_in[1];
  const float* bq = (const float*)d_in[2];
  const float* Wk = (const float*)d_in[3];
  const float* bk = (const float*)d_in[4];
  const float* Wv = (const float*)d_in[5];
  const float* bv = (const float*)d_in[6];
  float* out = (float*)d_out;
  char* ws = (char*)d_ws;

  u16*  qb   = (u16*)(ws + 0);            // 16,777,216
  u16*  kb   = (u16*)(ws + 16777216);     // 16,777,216
  u16*  vtb  = (u16*)(ws + 33554432);     // 16,777,216
  float* lsum = (float*)(ws + 50331648);  //     65,536
  u16*  P    = (u16*)(ws + 50397184);     // 67,108,864 (ends 117,506,048)
  u16*  xb   = (u16*)(ws + 50397184);     //  8,388,608 (alias P)
  u16*  Wt   = (u16*)(ws + 58785792);     //    786,432 (alias P)
  float* bcat = (float*)(ws + 59572224);  //      6,144 (alias P)
  u16*  vb   = (u16*)(ws + 59578368);     // 16,777,216 (alias P)

  k_convx<<<4096, 256, 0, stream>>>(x, xb, 16384 * 256 / 4);
  k_convw<<<1536, 256, 0, stream>>>(Wq, Wk, Wv, bq, bk, bv, Wt, bcat);
  k_proj<<<dim3(12, 128, 1), 256, 0, stream>>>(xb, Wt, bcat, qb, kb, vb);
  k_transv<<<dim3(8, 32, 8), 256, 0, stream>>>(vb, vtb);
  hipMemsetAsync(lsum, 0, 16384 * sizeof(float), stream);
  k_qk<<<dim3(16, 16, 8), 256, 0, stream>>>(qb, kb, P, lsum);
  k_pv<<<dim3(4, 16, 8), 256, 0, stream>>>(P, vtb, lsum, out);
}

// Round 3
// 238.409 us; speedup vs baseline: 1.0968x; 1.0021x over previous
//
#include <hip/hip_runtime.h>
#include <hip/hip_bf16.h>
#include <math.h>

typedef unsigned short u16;
using short8 = __attribute__((ext_vector_type(8))) short;
using f32x4  = __attribute__((ext_vector_type(4))) float;

#define BK 32

// ---------- helpers ----------

__device__ __forceinline__ u16 f2bf(float f) {
  union { float f; unsigned u; } v; v.f = f;
  unsigned r = v.u + 0x7FFFu + ((v.u >> 16) & 1u);   // RNE
  return (u16)(r >> 16);
}

__device__ __forceinline__ float fexp(float x) { return __expf(x); }

__device__ __forceinline__ void gld16(const void* g, void* l) {
  __builtin_amdgcn_global_load_lds(
      (const __attribute__((address_space(1))) void*)g,
      (__attribute__((address_space(3))) void*)l,
      16, 0, 0);
}

// ---------- 4-wave GEMM core (m97 pattern), group-reusable ----------
// 128x128 C tile of A[*,lda] @ B[*,ldb]^T, both row-major K-contiguous bf16.
// w = wave index within the 4-wave group (0..3), l = lane. As/Bs = 8KB each.

__device__ __forceinline__ void gemm_core4(const u16* __restrict__ Ag,
                                           const u16* __restrict__ Bg,
                                           int K, int lda, int ldb,
                                           u16* As, u16* Bs,
                                           f32x4 acc[4][4], int w, int l) {
  const int wm = (w & 1) << 6, wn = (w >> 1) << 6;
  const int ln = l & 15, lq = l >> 4;
  const int sr0 = w * 16 + (l >> 2);
  const int sr1 = 64 + sr0;
  const int sk = (l & 3) * 8;

#pragma unroll
  for (int mt = 0; mt < 4; mt++)
#pragma unroll
    for (int nt = 0; nt < 4; nt++) acc[mt][nt] = (f32x4)0.0f;

  for (int k0 = 0; k0 < K; k0 += BK) {
    __syncthreads();
    gld16(Ag + (size_t)sr0 * lda + k0 + sk, As + sr0 * BK + sk);
    gld16(Ag + (size_t)sr1 * lda + k0 + sk, As + sr1 * BK + sk);
    gld16(Bg + (size_t)sr0 * ldb + k0 + sk, Bs + sr0 * BK + sk);
    gld16(Bg + (size_t)sr1 * ldb + k0 + sk, Bs + sr1 * BK + sk);
    __syncthreads();
    short8 af[4], bf[4];
#pragma unroll
    for (int mt = 0; mt < 4; mt++)
      af[mt] = *(const short8*)(As + (wm + mt * 16 + ln) * BK + lq * 8);
#pragma unroll
    for (int nt = 0; nt < 4; nt++)
      bf[nt] = *(const short8*)(Bs + (wn + nt * 16 + ln) * BK + lq * 8);
#pragma unroll
    for (int mt = 0; mt < 4; mt++)
#pragma unroll
      for (int nt = 0; nt < 4; nt++)
        acc[mt][nt] = __builtin_amdgcn_mfma_f32_16x16x32_bf16(
            af[mt], bf[nt], acc[mt][nt], 0, 0, 0);
  }
}

// ---------- conversion kernels ----------

__global__ __launch_bounds__(256) void k_convx(const float* __restrict__ x,
                                               u16* __restrict__ xb, int n4) {
  int i = blockIdx.x * 256 + threadIdx.x;
  if (i < n4) {
    float4 v = ((const float4*)x)[i];
    ushort4 o;
    o.x = f2bf(v.x); o.y = f2bf(v.y); o.z = f2bf(v.z); o.w = f2bf(v.w);
    ((ushort4*)xb)[i] = o;
  }
}

__global__ __launch_bounds__(256) void k_convw(
    const float* __restrict__ Wq, const float* __restrict__ Wk,
    const float* __restrict__ Wv, const float* __restrict__ bq,
    const float* __restrict__ bk, const float* __restrict__ bv,
    u16* __restrict__ Wt, float* __restrict__ bcat) {
  int i = blockIdx.x * 256 + threadIdx.x;   // 1536*256 threads
  if (i < 1536 * 256) {
    int nn = i >> 8, e = i & 255;
    int sel = nn >> 9, c = nn & 511;
    const float* W = (sel == 0) ? Wq : (sel == 1) ? Wk : Wv;
    Wt[i] = f2bf(W[e * 512 + c]);           // W is [256][512] row-major
    if (e == 0) {
      const float* bb = (sel == 0) ? bq : (sel == 1) ? bk : bv;
      bcat[nn] = bb[c];
    }
  }
}

// ---------- projection GEMM: [16384,256] @ Wt^T -> q(sigmoid),k,v bf16 ----------

__global__ __launch_bounds__(256) void k_proj(
    const u16* __restrict__ xb, const u16* __restrict__ Wt,
    const float* __restrict__ bcat, u16* __restrict__ qb,
    u16* __restrict__ kb, u16* __restrict__ vb) {
  __shared__ __align__(16) u16 As[128 * BK];
  __shared__ __align__(16) u16 Bs[128 * BK];
  const int bm = blockIdx.y * 128, bn = blockIdx.x * 128;
  const int tid = threadIdx.x, w = tid >> 6, l = tid & 63;
  f32x4 acc[4][4];
  gemm_core4(xb + (size_t)bm * 256, Wt + (size_t)bn * 256, 256, 256, 256,
             As, Bs, acc, w, l);

  const int wm = (w & 1) << 6, wn = (w >> 1) << 6;
  const int ln = l & 15, lq = l >> 4;
  // block-uniform output selection: N=1536 = 3x512, BN=128 divides 512.
  const int sel = blockIdx.x >> 2;          // 0=q, 1=k, 2=v
  u16* dst = (sel == 0) ? qb : (sel == 1) ? kb : vb;
  const int cb = (blockIdx.x & 3) * 128;    // column base within the 512 range
#pragma unroll
  for (int mt = 0; mt < 4; mt++)
#pragma unroll
    for (int r = 0; r < 4; r++) {
      int row = bm + wm + mt * 16 + lq * 4 + r;
#pragma unroll
      for (int nt = 0; nt < 4; nt++) {
        int col = wn + nt * 16 + ln;
        float v = acc[mt][nt][r] + bcat[bn + col];
        float ov = (sel == 0) ? __builtin_amdgcn_rcpf(1.0f + fexp(-v)) : v;
        dst[(size_t)row * 512 + cb + col] = f2bf(ov);
      }
    }
}

// ---------- V transpose: vb[b][t][v] -> vtb[b][v][t], ushort4 both ways ----------

__global__ __launch_bounds__(256) void k_transv(const u16* __restrict__ vb,
                                                u16* __restrict__ vtb) {
  const int b = blockIdx.z;
  const int t0 = blockIdx.y * 64, v0 = blockIdx.x * 64;
  __shared__ u16 tl[64][68];
  const u16* src = vb + (size_t)b * 2048 * 512;
  u16* dst = vtb + (size_t)b * 512 * 2048;
  for (int i = threadIdx.x; i < 1024; i += 256) {
    int r = i >> 4, c4 = (i & 15) * 4;
    *(ushort4*)&tl[r][c4] =
        *(const ushort4*)&src[(size_t)(t0 + r) * 512 + v0 + c4];
  }
  __syncthreads();
  for (int i = threadIdx.x; i < 1024; i += 256) {
    int r = i >> 4, c4 = (i & 15) * 4;
    ushort4 o;
    o.x = tl[c4 + 0][r]; o.y = tl[c4 + 1][r];
    o.z = tl[c4 + 2][r]; o.w = tl[c4 + 3][r];
    *(ushort4*)&dst[(size_t)(v0 + r) * 2048 + t0 + c4] = o;
  }
}

// ---------- QK^T + elu + exp -> P (bf16), row sums via atomics ----------

__global__ __launch_bounds__(256) void k_qk(const u16* __restrict__ qb,
                                            const u16* __restrict__ kb,
                                            u16* __restrict__ P,
                                            float* __restrict__ lsum) {
  __shared__ __align__(16) u16 As[128 * BK];
  __shared__ __align__(16) u16 Bs[128 * BK];
  const int b = blockIdx.z;
  const int bm = blockIdx.y * 128, bn = blockIdx.x * 128;
  const size_t ob = (size_t)b * 2048 * 512;
  const int tid = threadIdx.x, w = tid >> 6, l = tid & 63;
  f32x4 acc[4][4];
  gemm_core4(qb + ob + (size_t)bm * 512, kb + ob + (size_t)bn * 512,
             512, 512, 512, As, Bs, acc, w, l);

  const int wm = (w & 1) << 6, wn = (w >> 1) << 6;
  const int ln = l & 15, lq = l >> 4;
  const float scale = 0.0625f;  // 1/sqrt(256)
#pragma unroll
  for (int mt = 0; mt < 4; mt++)
#pragma unroll
    for (int r = 0; r < 4; r++) {
      int row = bm + wm + mt * 16 + lq * 4 + r;
      float s = 0.0f;
#pragma unroll
      for (int nt = 0; nt < 4; nt++) {
        int col = bn + wn + nt * 16 + ln;
        float v = acc[mt][nt][r] * scale;
        float e = (v > 0.0f) ? v : (fexp(v) - 1.0f);   // elu (hw exp)
        float p = fexp(e);    // unnormalized softmax (elu >= -1, no max sub)
        P[((size_t)b * 2048 + row) * 2048 + col] = f2bf(p);
        s += p;
      }
#pragma unroll
      for (int o = 1; o < 16; o <<= 1) s += __shfl_xor(s, o);
      if (ln == 0) atomicAdd(&lsum[b * 2048 + row], s);
    }
}

// ---------- P @ V with in-block split-K (2 groups x 4 waves) ----------

__global__ __launch_bounds__(512, 4) void k_pv(const u16* __restrict__ P,
                                               const u16* __restrict__ vtb,
                                               const float* __restrict__ lsum,
                                               float* __restrict__ out) {
  __shared__ __align__(16) u16 smem[16384];   // 32 KB: As0|Bs0|As1|Bs1
  const int b = blockIdx.z;
  const int bm = blockIdx.y * 128, bn = blockIdx.x * 128;
  const int tid = threadIdx.x;
  const int g = tid >> 8;           // K-split group 0/1
  const int t = tid & 255;
  const int w = t >> 6, l = t & 63;
  u16* As = smem + g * 8192;
  u16* Bs = smem + g * 8192 + 4096;

  f32x4 acc[4][4];
  gemm_core4(P  + (size_t)b * 2048 * 2048 + (size_t)bm * 2048 + g * 1024,
             vtb + (size_t)b * 512 * 2048 + (size_t)bn * 2048 + g * 1024,
             1024, 2048, 2048, As, Bs, acc, w, l);

  // cross-group reduction via LDS: 2 rounds of 32 KB (mt pairs)
  f32x4* red = (f32x4*)smem;        // 2048 entries = 32 KB
#pragma unroll
  for (int half = 0; half < 2; half++) {
    __syncthreads();
    if (g == 1) {
#pragma unroll
      for (int m2 = 0; m2 < 2; m2++)
#pragma unroll
        for (int nt = 0; nt < 4; nt++)
          red[((m2 * 4 + nt) * 4 + w) * 64 + l] = acc[half * 2 + m2][nt];
    }
    __syncthreads();
    if (g == 0) {
#pragma unroll
      for (int m2 = 0; m2 < 2; m2++)
#pragma unroll
        for (int nt = 0; nt < 4; nt++)
          acc[half * 2 + m2][nt] += red[((m2 * 4 + nt) * 4 + w) * 64 + l];
    }
  }

  if (g == 0) {
    const int wm = (w & 1) << 6, wn = (w >> 1) << 6;
    const int ln = l & 15, lq = l >> 4;
#pragma unroll
    for (int mt = 0; mt < 4; mt++)
#pragma unroll
      for (int r = 0; r < 4; r++) {
        int row = bm + wm + mt * 16 + lq * 4 + r;
        float inv = 1.0f / lsum[b * 2048 + row];
#pragma unroll
        for (int nt = 0; nt < 4; nt++) {
          int col = bn + wn + nt * 16 + ln;
          out[((size_t)b * 2048 + row) * 512 + col] = acc[mt][nt][r] * inv;
        }
      }
  }
}

// ---------- launch ----------

extern "C" void kernel_launch(void* const* d_in, const int* in_sizes, int n_in,
                              void* d_out, int out_size, void* d_ws, size_t ws_size,
                              hipStream_t stream) {
  const float* x  = (const float*)d_in[0];
  const float* Wq = (const float*)d_in[1];
  const float* bq = (const float*)d_in[2];
  const float* Wk = (const float*)d_in[3];
  const float* bk = (const float*)d_in[4];
  const float* Wv = (const float*)d_in[5];
  const float* bv = (const float*)d_in[6];
  float* out = (float*)d_out;
  char* ws = (char*)d_ws;

  u16*  qb   = (u16*)(ws + 0);            // 16,777,216
  u16*  kb   = (u16*)(ws + 16777216);     // 16,777,216
  u16*  vtb  = (u16*)(ws + 33554432);     // 16,777,216
  float* lsum = (float*)(ws + 50331648);  //     65,536
  u16*  P    = (u16*)(ws + 50397184);     // 67,108,864 (ends 117,506,048)
  u16*  xb   = (u16*)(ws + 50397184);     //  8,388,608 (alias P)
  u16*  Wt   = (u16*)(ws + 58785792);     //    786,432 (alias P)
  float* bcat = (float*)(ws + 59572224);  //      6,144 (alias P)
  u16*  vb   = (u16*)(ws + 59578368);     // 16,777,216 (alias P)

  k_convx<<<4096, 256, 0, stream>>>(x, xb, 16384 * 256 / 4);
  k_convw<<<1536, 256, 0, stream>>>(Wq, Wk, Wv, bq, bk, bv, Wt, bcat);
  k_proj<<<dim3(12, 128, 1), 256, 0, stream>>>(xb, Wt, bcat, qb, kb, vb);
  k_transv<<<dim3(8, 32, 8), 256, 0, stream>>>(vb, vtb);
  hipMemsetAsync(lsum, 0, 16384 * sizeof(float), stream);
  k_qk<<<dim3(16, 16, 8), 256, 0, stream>>>(qb, kb, P, lsum);
  k_pv<<<dim3(4, 16, 8), 512, 0, stream>>>(P, vtb, lsum, out);
}

// Round 4
// 228.516 us; speedup vs baseline: 1.1442x; 1.0433x over previous
//
#include <hip/hip_runtime.h>
#include <hip/hip_bf16.h>
#include <math.h>

typedef unsigned short u16;
using short8 = __attribute__((ext_vector_type(8))) short;
using f32x4  = __attribute__((ext_vector_type(4))) float;

#define BK 32

// ---------- helpers ----------

__device__ __forceinline__ u16 f2bf(float f) {
  union { float f; unsigned u; } v; v.f = f;
  unsigned r = v.u + 0x7FFFu + ((v.u >> 16) & 1u);   // RNE
  return (u16)(r >> 16);
}

__device__ __forceinline__ float fexp(float x) { return __expf(x); }

__device__ __forceinline__ void gld16(const void* g, void* l) {
  __builtin_amdgcn_global_load_lds(
      (const __attribute__((address_space(1))) void*)g,
      (__attribute__((address_space(3))) void*)l,
      16, 0, 0);
}

// ---------- 4-wave GEMM core (m97 pattern) ----------
// 128x128 C tile of A[*,lda] @ B[*,ldb]^T, both row-major K-contiguous bf16.

__device__ __forceinline__ void gemm_core4(const u16* __restrict__ Ag,
                                           const u16* __restrict__ Bg,
                                           int K, int lda, int ldb,
                                           u16* As, u16* Bs,
                                           f32x4 acc[4][4], int w, int l) {
  const int wm = (w & 1) << 6, wn = (w >> 1) << 6;
  const int ln = l & 15, lq = l >> 4;
  const int sr0 = w * 16 + (l >> 2);
  const int sr1 = 64 + sr0;
  const int sk = (l & 3) * 8;

#pragma unroll
  for (int mt = 0; mt < 4; mt++)
#pragma unroll
    for (int nt = 0; nt < 4; nt++) acc[mt][nt] = (f32x4)0.0f;

  for (int k0 = 0; k0 < K; k0 += BK) {
    __syncthreads();
    gld16(Ag + (size_t)sr0 * lda + k0 + sk, As + sr0 * BK + sk);
    gld16(Ag + (size_t)sr1 * lda + k0 + sk, As + sr1 * BK + sk);
    gld16(Bg + (size_t)sr0 * ldb + k0 + sk, Bs + sr0 * BK + sk);
    gld16(Bg + (size_t)sr1 * ldb + k0 + sk, Bs + sr1 * BK + sk);
    __syncthreads();
    short8 af[4], bf[4];
#pragma unroll
    for (int mt = 0; mt < 4; mt++)
      af[mt] = *(const short8*)(As + (wm + mt * 16 + ln) * BK + lq * 8);
#pragma unroll
    for (int nt = 0; nt < 4; nt++)
      bf[nt] = *(const short8*)(Bs + (wn + nt * 16 + ln) * BK + lq * 8);
#pragma unroll
    for (int mt = 0; mt < 4; mt++)
#pragma unroll
      for (int nt = 0; nt < 4; nt++)
        acc[mt][nt] = __builtin_amdgcn_mfma_f32_16x16x32_bf16(
            af[mt], bf[nt], acc[mt][nt], 0, 0, 0);
  }
}

// ---------- merged conversion kernel ----------
// blocks [0,4096): x -> xb (bf16, float4-vectorized)
// blocks [4096,5632): Wq/Wk/Wv -> Wt[1536][256] bf16 (transposed) + bcat

__global__ __launch_bounds__(256) void k_conv(
    const float* __restrict__ x, u16* __restrict__ xb,
    const float* __restrict__ Wq, const float* __restrict__ Wk,
    const float* __restrict__ Wv, const float* __restrict__ bq,
    const float* __restrict__ bk, const float* __restrict__ bv,
    u16* __restrict__ Wt, float* __restrict__ bcat) {
  const int bid = blockIdx.x;
  if (bid < 4096) {
    int i = bid * 256 + threadIdx.x;     // 1,048,576 float4s
    float4 v = ((const float4*)x)[i];
    ushort4 o;
    o.x = f2bf(v.x); o.y = f2bf(v.y); o.z = f2bf(v.z); o.w = f2bf(v.w);
    ((ushort4*)xb)[i] = o;
  } else {
    int i = (bid - 4096) * 256 + threadIdx.x;   // 393,216
    int nn = i >> 8, e = i & 255;
    int sel = nn >> 9, c = nn & 511;
    const float* W = (sel == 0) ? Wq : (sel == 1) ? Wk : Wv;
    Wt[i] = f2bf(W[e * 512 + c]);               // W is [256][512] row-major
    if (e == 0) {
      const float* bb = (sel == 0) ? bq : (sel == 1) ? bk : bv;
      bcat[nn] = bb[c];
    }
  }
}

// ---------- projection GEMM + fused V transpose ----------
// [16384,256] @ Wt^T. q: sigmoid -> qb row-major. k -> kb row-major.
// v: bias-add -> vtb[b][vcol][t] via in-LDS transpose (coalesced stores).

__global__ __launch_bounds__(256) void k_proj(
    const u16* __restrict__ xb, const u16* __restrict__ Wt,
    const float* __restrict__ bcat, u16* __restrict__ qb,
    u16* __restrict__ kb, u16* __restrict__ vtb) {
  __shared__ __align__(16) u16 smem[8704];   // staging 8192; v-repack 128*68
  u16* As = smem;
  u16* Bs = smem + 4096;
  const int bm = blockIdx.y * 128, bn = blockIdx.x * 128;
  const int tid = threadIdx.x, w = tid >> 6, l = tid & 63;
  f32x4 acc[4][4];
  gemm_core4(xb + (size_t)bm * 256, Wt + (size_t)bn * 256, 256, 256, 256,
             As, Bs, acc, w, l);

  const int wm = (w & 1) << 6, wn = (w >> 1) << 6;
  const int ln = l & 15, lq = l >> 4;
  const int sel = blockIdx.x >> 2;          // 0=q, 1=k, 2=v (block-uniform)
  const int cb = (blockIdx.x & 3) * 128;    // col base within the 512 range

  if (sel < 2) {
    u16* dst = sel ? kb : qb;
#pragma unroll
    for (int mt = 0; mt < 4; mt++)
#pragma unroll
      for (int r = 0; r < 4; r++) {
        int row = bm + wm + mt * 16 + lq * 4 + r;
#pragma unroll
        for (int nt = 0; nt < 4; nt++) {
          int col = wn + nt * 16 + ln;
          float v = acc[mt][nt][r] + bcat[bn + col];
          float ov = (sel == 0) ? __builtin_amdgcn_rcpf(1.0f + fexp(-v)) : v;
          dst[(size_t)row * 512 + cb + col] = f2bf(ov);
        }
      }
  } else {
    // V path: 2 rounds of 64 rows; write transposed tile [col][row] into LDS,
    // read back rows (= v columns) and store coalesced into vtb[b][vcol][t].
    const int b = bm >> 11, t0 = bm & 2047;
#pragma unroll
    for (int h = 0; h < 2; h++) {
      __syncthreads();
      if ((w & 1) == h) {
#pragma unroll
        for (int mt = 0; mt < 4; mt++)
#pragma unroll
          for (int nt = 0; nt < 4; nt++) {
            int c = wn + nt * 16 + ln;
            float bias = bcat[bn + c];
#pragma unroll
            for (int r = 0; r < 4; r++) {
              int lr = mt * 16 + lq * 4 + r;          // 0..63
              smem[c * 68 + lr] = f2bf(acc[mt][nt][r] + bias);
            }
          }
      }
      __syncthreads();
      int c2 = tid >> 1, half = tid & 1;              // c2: 0..127
      size_t dbase = ((size_t)b * 512 + cb + c2) * 2048 + t0 + h * 64 + half * 32;
#pragma unroll
      for (int j = 0; j < 4; j++) {
        ushort4 a0 = *(const ushort4*)&smem[c2 * 68 + half * 32 + j * 8];
        ushort4 a1 = *(const ushort4*)&smem[c2 * 68 + half * 32 + j * 8 + 4];
        *(ushort4*)&vtb[dbase + j * 8] = a0;
        *(ushort4*)&vtb[dbase + j * 8 + 4] = a1;
      }
    }
  }
}

// ---------- QK^T + elu + exp -> P (bf16), row sums via atomics ----------
// __launch_bounds__(256,4): cap regs at 128 -> 4 waves/SIMD (was 140 -> 3).

__global__ __launch_bounds__(256, 4) void k_qk(const u16* __restrict__ qb,
                                               const u16* __restrict__ kb,
                                               u16* __restrict__ P,
                                               float* __restrict__ lsum) {
  __shared__ __align__(16) u16 As[128 * BK];
  __shared__ __align__(16) u16 Bs[128 * BK];
  const int b = blockIdx.z;
  const int bm = blockIdx.y * 128, bn = blockIdx.x * 128;
  const size_t ob = (size_t)b * 2048 * 512;
  const int tid = threadIdx.x, w = tid >> 6, l = tid & 63;
  f32x4 acc[4][4];
  gemm_core4(qb + ob + (size_t)bm * 512, kb + ob + (size_t)bn * 512,
             512, 512, 512, As, Bs, acc, w, l);

  const int wm = (w & 1) << 6, wn = (w >> 1) << 6;
  const int ln = l & 15, lq = l >> 4;
  const float scale = 0.0625f;  // 1/sqrt(256)
#pragma unroll
  for (int mt = 0; mt < 4; mt++)
#pragma unroll
    for (int r = 0; r < 4; r++) {
      int row = bm + wm + mt * 16 + lq * 4 + r;
      float s = 0.0f;
#pragma unroll
      for (int nt = 0; nt < 4; nt++) {
        int col = bn + wn + nt * 16 + ln;
        float v = acc[mt][nt][r] * scale;
        float e = (v > 0.0f) ? v : (fexp(v) - 1.0f);   // elu (hw exp)
        float p = fexp(e);    // unnormalized softmax (elu >= -1, no max sub)
        P[((size_t)b * 2048 + row) * 2048 + col] = f2bf(p);
        s += p;
      }
#pragma unroll
      for (int o = 1; o < 16; o <<= 1) s += __shfl_xor(s, o);
      if (ln == 0) atomicAdd(&lsum[b * 2048 + row], s);
    }
}

// ---------- P @ V, divide by row sum, fp32 out (simple 256-thr core) ----------

__global__ __launch_bounds__(256) void k_pv(const u16* __restrict__ P,
                                            const u16* __restrict__ vtb,
                                            const float* __restrict__ lsum,
                                            float* __restrict__ out) {
  __shared__ __align__(16) u16 As[128 * BK];
  __shared__ __align__(16) u16 Bs[128 * BK];
  const int b = blockIdx.z;
  const int bm = blockIdx.y * 128, bn = blockIdx.x * 128;
  const int tid = threadIdx.x, w = tid >> 6, l = tid & 63;
  f32x4 acc[4][4];
  gemm_core4(P  + (size_t)b * 2048 * 2048 + (size_t)bm * 2048,
             vtb + (size_t)b * 512 * 2048 + (size_t)bn * 2048,
             2048, 2048, 2048, As, Bs, acc, w, l);

  const int wm = (w & 1) << 6, wn = (w >> 1) << 6;
  const int ln = l & 15, lq = l >> 4;
#pragma unroll
  for (int mt = 0; mt < 4; mt++)
#pragma unroll
    for (int r = 0; r < 4; r++) {
      int row = bm + wm + mt * 16 + lq * 4 + r;
      float inv = 1.0f / lsum[b * 2048 + row];
#pragma unroll
      for (int nt = 0; nt < 4; nt++) {
        int col = bn + wn + nt * 16 + ln;
        out[((size_t)b * 2048 + row) * 512 + col] = acc[mt][nt][r] * inv;
      }
    }
}

// ---------- launch ----------

extern "C" void kernel_launch(void* const* d_in, const int* in_sizes, int n_in,
                              void* d_out, int out_size, void* d_ws, size_t ws_size,
                              hipStream_t stream) {
  const float* x  = (const float*)d_in[0];
  const float* Wq = (const float*)d_in[1];
  const float* bq = (const float*)d_in[2];
  const float* Wk = (const float*)d_in[3];
  const float* bk = (const float*)d_in[4];
  const float* Wv = (const float*)d_in[5];
  const float* bv = (const float*)d_in[6];
  float* out = (float*)d_out;
  char* ws = (char*)d_ws;

  u16*  qb   = (u16*)(ws + 0);            // 16,777,216
  u16*  kb   = (u16*)(ws + 16777216);     // 16,777,216
  u16*  vtb  = (u16*)(ws + 33554432);     // 16,777,216
  float* lsum = (float*)(ws + 50331648);  //     65,536
  u16*  P    = (u16*)(ws + 50397184);     // 67,108,864 (ends 117,506,048)
  u16*  xb   = (u16*)(ws + 50397184);     //  8,388,608 (alias P)
  u16*  Wt   = (u16*)(ws + 58785792);     //    786,432 (alias P)
  float* bcat = (float*)(ws + 59572224);  //      6,144 (alias P)

  k_conv<<<5632, 256, 0, stream>>>(x, xb, Wq, Wk, Wv, bq, bk, bv, Wt, bcat);
  k_proj<<<dim3(12, 128, 1), 256, 0, stream>>>(xb, Wt, bcat, qb, kb, vtb);
  hipMemsetAsync(lsum, 0, 16384 * sizeof(float), stream);
  k_qk<<<dim3(16, 16, 8), 256, 0, stream>>>(qb, kb, P, lsum);
  k_pv<<<dim3(4, 16, 8), 256, 0, stream>>>(P, vtb, lsum, out);
}